// Round 4
// baseline (1599.497 us; speedup 1.0000x reference)
//
#include <hip/hip_runtime.h>

// SVF 3D scaling-and-squaring, round 3 (resubmit — round 3 hit GPUAcquisitionTimeout).
// disp0 = v*2^-32; 32x: disp = disp + trilinear(disp, id+disp); out = (id+disp, disp).
// Changes vs round 2:
//  - steps 0..25: tiled-LDS stencil kernel (offsets < ~1 voxel there). 8x8x4 tile,
//    halo 2, per-lane EXACT global fallback if a corner leaves the halo -> results
//    stay bit-identical to the pure-gather pipeline regardless of field magnitude.
//  - svf_init fused into step 0 (stages from planar v, scaling by 2^-32).
//  - svf_final fused into step 31 (writes 6 planar output channels directly).
//  - steps 26..31: round-2 scatter-gather kernel (address-rate bound, ~93% of model).

#define NSTEPS 32

constexpr int VOX = 1 << 21;        // 128^3
constexpr int NV  = 2 * VOX;
constexpr int THREADS = 256;
constexpr int NBLK = NV / THREADS;  // 16384
constexpr int NXCD = 8;
constexpr int K_TILED = 26;         // steps 0..25 use the tiled kernel

// [0..127]=x-table, [128..255]=y, [256..383]=z (bit-exact, from input idg)
__device__ float g_tab[3 * 128];

__global__ __launch_bounds__(128) void extract_tables(const float* __restrict__ idg) {
    int t = threadIdx.x;
    g_tab[t]       = idg[3 * t];              // [0,0,x,0]
    g_tab[128 + t] = idg[3 * (t << 7) + 1];   // [0,y,0,1]
    g_tab[256 + t] = idg[3 * (t << 14) + 2];  // [z,0,0,2]
}

__device__ __forceinline__ float4 trilerp_accum(
    float4 d, float4 g000, float4 g001, float4 g010, float4 g011,
    float4 g100, float4 g101, float4 g110, float4 g111,
    float fx, float fy, float fz) {
    float wx0 = 1.0f - fx, wy0 = 1.0f - fy, wz0 = 1.0f - fz;
    float w000 = wz0 * wy0 * wx0;
    float w001 = wz0 * wy0 * fx;
    float w010 = wz0 * fy  * wx0;
    float w011 = wz0 * fy  * fx;
    float w100 = fz  * wy0 * wx0;
    float w101 = fz  * wy0 * fx;
    float w110 = fz  * fy  * wx0;
    float w111 = fz  * fy  * fx;
    float ox = g000.x * w000 + g001.x * w001 + g010.x * w010 + g011.x * w011
             + g100.x * w100 + g101.x * w101 + g110.x * w110 + g111.x * w111;
    float oy = g000.y * w000 + g001.y * w001 + g010.y * w010 + g011.y * w011
             + g100.y * w100 + g101.y * w101 + g110.y * w110 + g111.y * w111;
    float oz = g000.z * w000 + g001.z * w001 + g010.z * w010 + g011.z * w011
             + g100.z * w100 + g101.z * w101 + g110.z * w110 + g111.z * w111;
    return make_float4(d.x + ox, d.y + oy, d.z + oz, 0.0f);
}

// ---------------- tiled stencil kernel, steps 0..25 ----------------
// block = 256 threads mapping an 8x8x4 (x,y,z) tile; LDS holds tile+halo(2):
// 12x12x8 voxels, x padded to 13 for bank spread.
template<bool FIRST>
__global__ __launch_bounds__(THREADS, 4) void svf_step_tiled(
        const float4* __restrict__ src, const float* __restrict__ v,
        float4* __restrict__ dst) {
    __shared__ float4 tile[8][12][13];  // [lz][ly][lx(pad)]

    // XCD-chunked swizzle (16384 % 8 == 0)
    int bid = blockIdx.x;
    int swz = (bid & (NXCD - 1)) * (NBLK / NXCD) + (bid >> 3);
    int n = swz >> 13;              // 8192 tiles per batch
    int t = swz & 8191;
    int bx0 = (t & 15) << 3;        // 16 x-tiles
    int by0 = ((t >> 4) & 15) << 3; // 16 y-tiles
    int bz0 = (t >> 8) << 2;        // 32 z-tiles of depth 4

    const int nbase  = n << 21;
    const int nbase3 = 3 * nbase;
    const float sc = 2.3283064365386963e-10f;  // 2^-32

    int tid = threadIdx.x;
    // stage tile + halo (1152 voxels), border-clamped
    for (int idx = tid; idx < 8 * 12 * 12; idx += THREADS) {
        int lx = idx % 12;
        int r  = idx / 12;
        int ly = r % 12;
        int lz = r / 12;
        int gx = min(max(bx0 + lx - 2, 0), 127);
        int gy = min(max(by0 + ly - 2, 0), 127);
        int gz = min(max(bz0 + lz - 2, 0), 127);
        int s = (gz << 14) + (gy << 7) + gx;
        float4 val;
        if (FIRST) {
            int b = nbase3 + s;
            val = make_float4(v[b] * sc, v[b + VOX] * sc, v[b + 2 * VOX] * sc, 0.0f);
        } else {
            val = src[nbase + s];
        }
        tile[lz][ly][lx] = val;
    }
    __syncthreads();

    int tx = tid & 7, ty = (tid >> 3) & 7, tz = tid >> 6;
    int gx = bx0 + tx, gy = by0 + ty, gz = bz0 + tz;
    int s = (gz << 14) + (gy << 7) + gx;

    float4 d = tile[tz + 2][ty + 2][tx + 2];  // own voxel (fused init read)
    float id_x = g_tab[gx];
    float id_y = g_tab[128 + gy];
    float id_z = g_tab[256 + gz];

    float ix = ((id_x + d.x) + 1.0f) * 0.5f * 127.0f;
    float iy = ((id_y + d.y) + 1.0f) * 0.5f * 127.0f;
    float iz = ((id_z + d.z) + 1.0f) * 0.5f * 127.0f;
    ix = fminf(fmaxf(ix, 0.0f), 127.0f);
    iy = fminf(fmaxf(iy, 0.0f), 127.0f);
    iz = fminf(fmaxf(iz, 0.0f), 127.0f);

    float x0f = floorf(ix), y0f = floorf(iy), z0f = floorf(iz);
    float fx = ix - x0f, fy = iy - y0f, fz = iz - z0f;
    int x0 = (int)x0f, y0 = (int)y0f, z0 = (int)z0f;
    int x1 = min(x0 + 1, 127);
    int y1 = min(y0 + 1, 127);
    int z1 = min(z0 + 1, 127);

    int lx0 = x0 - bx0 + 2, lx1 = x1 - bx0 + 2;
    int ly0 = y0 - by0 + 2, ly1 = y1 - by0 + 2;
    int lz0 = z0 - bz0 + 2, lz1 = z1 - bz0 + 2;
    bool inT = (unsigned)lx0 < 12u && (unsigned)lx1 < 12u
            && (unsigned)ly0 < 12u && (unsigned)ly1 < 12u
            && (unsigned)lz0 < 8u  && (unsigned)lz1 < 8u;

    float4 g000, g001, g010, g011, g100, g101, g110, g111;
    if (inT) {
        g000 = tile[lz0][ly0][lx0];
        g001 = tile[lz0][ly0][lx1];
        g010 = tile[lz0][ly1][lx0];
        g011 = tile[lz0][ly1][lx1];
        g100 = tile[lz1][ly0][lx0];
        g101 = tile[lz1][ly0][lx1];
        g110 = tile[lz1][ly1][lx0];
        g111 = tile[lz1][ly1][lx1];
    } else {
        // exact fallback: identical values from global
        int r00 = (z0 << 14) + (y0 << 7);
        int r01 = (z0 << 14) + (y1 << 7);
        int r10 = (z1 << 14) + (y0 << 7);
        int r11 = (z1 << 14) + (y1 << 7);
        if (FIRST) {
            auto ldv = [&](int ss) {
                int b = nbase3 + ss;
                return make_float4(v[b] * sc, v[b + VOX] * sc, v[b + 2 * VOX] * sc, 0.0f);
            };
            g000 = ldv(r00 + x0); g001 = ldv(r00 + x1);
            g010 = ldv(r01 + x0); g011 = ldv(r01 + x1);
            g100 = ldv(r10 + x0); g101 = ldv(r10 + x1);
            g110 = ldv(r11 + x0); g111 = ldv(r11 + x1);
        } else {
            g000 = src[nbase + r00 + x0]; g001 = src[nbase + r00 + x1];
            g010 = src[nbase + r01 + x0]; g011 = src[nbase + r01 + x1];
            g100 = src[nbase + r10 + x0]; g101 = src[nbase + r10 + x1];
            g110 = src[nbase + r11 + x0]; g111 = src[nbase + r11 + x1];
        }
    }

    dst[nbase + s] = trilerp_accum(d, g000, g001, g010, g011,
                                   g100, g101, g110, g111, fx, fy, fz);
}

// ---------------- scatter-gather kernel, steps 26..30 ----------------
__global__ __launch_bounds__(THREADS) void svf_step(const float4* __restrict__ src,
                                                    float4* __restrict__ dst) {
    int bid = blockIdx.x;
    int swz = (bid & (NXCD - 1)) * (NBLK / NXCD) + (bid >> 3);
    int i = swz * THREADS + threadIdx.x;
    int s = i & (VOX - 1);
    int base = i - s;

    int xg = s & 127, yg = (s >> 7) & 127, zg = s >> 14;

    float4 d = src[i];
    float ix = ((g_tab[xg] + d.x) + 1.0f) * 0.5f * 127.0f;
    float iy = ((g_tab[128 + yg] + d.y) + 1.0f) * 0.5f * 127.0f;
    float iz = ((g_tab[256 + zg] + d.z) + 1.0f) * 0.5f * 127.0f;
    ix = fminf(fmaxf(ix, 0.0f), 127.0f);
    iy = fminf(fmaxf(iy, 0.0f), 127.0f);
    iz = fminf(fmaxf(iz, 0.0f), 127.0f);

    float x0f = floorf(ix), y0f = floorf(iy), z0f = floorf(iz);
    float fx = ix - x0f, fy = iy - y0f, fz = iz - z0f;
    int x0 = (int)x0f, y0 = (int)y0f, z0 = (int)z0f;
    int x1 = min(x0 + 1, 127), y1 = min(y0 + 1, 127), z1 = min(z0 + 1, 127);

    int r00 = base + (z0 << 14) + (y0 << 7);
    int r01 = base + (z0 << 14) + (y1 << 7);
    int r10 = base + (z1 << 14) + (y0 << 7);
    int r11 = base + (z1 << 14) + (y1 << 7);

    dst[i] = trilerp_accum(d, src[r00 + x0], src[r00 + x1], src[r01 + x0], src[r01 + x1],
                           src[r10 + x0], src[r10 + x1], src[r11 + x0], src[r11 + x1],
                           fx, fy, fz);
}

// ---------------- last step fused with output formatting ----------------
__global__ __launch_bounds__(THREADS) void svf_step_last(const float4* __restrict__ src,
                                                         float* __restrict__ out) {
    int bid = blockIdx.x;
    int swz = (bid & (NXCD - 1)) * (NBLK / NXCD) + (bid >> 3);
    int i = swz * THREADS + threadIdx.x;
    int s = i & (VOX - 1);
    int base = i - s;
    int n = i >> 21;

    int xg = s & 127, yg = (s >> 7) & 127, zg = s >> 14;
    float id_x = g_tab[xg], id_y = g_tab[128 + yg], id_z = g_tab[256 + zg];

    float4 d = src[i];
    float ix = ((id_x + d.x) + 1.0f) * 0.5f * 127.0f;
    float iy = ((id_y + d.y) + 1.0f) * 0.5f * 127.0f;
    float iz = ((id_z + d.z) + 1.0f) * 0.5f * 127.0f;
    ix = fminf(fmaxf(ix, 0.0f), 127.0f);
    iy = fminf(fmaxf(iy, 0.0f), 127.0f);
    iz = fminf(fmaxf(iz, 0.0f), 127.0f);

    float x0f = floorf(ix), y0f = floorf(iy), z0f = floorf(iz);
    float fx = ix - x0f, fy = iy - y0f, fz = iz - z0f;
    int x0 = (int)x0f, y0 = (int)y0f, z0 = (int)z0f;
    int x1 = min(x0 + 1, 127), y1 = min(y0 + 1, 127), z1 = min(z0 + 1, 127);

    int r00 = base + (z0 << 14) + (y0 << 7);
    int r01 = base + (z0 << 14) + (y1 << 7);
    int r10 = base + (z1 << 14) + (y0 << 7);
    int r11 = base + (z1 << 14) + (y1 << 7);

    float4 nd = trilerp_accum(d, src[r00 + x0], src[r00 + x1], src[r01 + x0], src[r01 + x1],
                              src[r10 + x0], src[r10 + x1], src[r11 + x0], src[r11 + x1],
                              fx, fy, fz);

    int ob = n * 3 * VOX + s;
    out[ob]           = id_x + nd.x;
    out[ob + VOX]     = id_y + nd.y;
    out[ob + 2 * VOX] = id_z + nd.z;
    float* dout = out + (size_t)2 * 3 * VOX;
    dout[ob]           = nd.x;
    dout[ob + VOX]     = nd.y;
    dout[ob + 2 * VOX] = nd.z;
}

extern "C" void kernel_launch(void* const* d_in, const int* in_sizes, int n_in,
                              void* d_out, int out_size, void* d_ws, size_t ws_size,
                              hipStream_t stream) {
    const float* v   = (const float*)d_in[0];
    const float* idg = (const float*)d_in[1];
    float* out = (float*)d_out;

    // Ping-pong: A in workspace, B aliased onto d_out (scratch until the fused
    // last step fully rewrites d_out; last step reads only A).
    float4* A = (float4*)d_ws;
    float4* B = (float4*)d_out;

    dim3 grid(NBLK), block(THREADS);

    extract_tables<<<1, 128, 0, stream>>>(idg);
    // step 0 (init fused): v -> A
    svf_step_tiled<true><<<grid, block, 0, stream>>>(nullptr, v, A);
    // steps 1..K_TILED-1: tiled. odd: A->B, even: B->A
    for (int k = 1; k < K_TILED; ++k) {
        const float4* srck = (k & 1) ? (const float4*)A : (const float4*)B;
        float4*       dstk = (k & 1) ? B : A;
        svf_step_tiled<false><<<grid, block, 0, stream>>>(srck, nullptr, dstk);
    }
    // steps K_TILED..30: scatter-gather
    for (int k = K_TILED; k < NSTEPS - 1; ++k) {
        const float4* srck = (k & 1) ? (const float4*)A : (const float4*)B;
        float4*       dstk = (k & 1) ? B : A;
        svf_step<<<grid, block, 0, stream>>>(srck, dstk);
    }
    // step 31 (odd) reads A, writes final planar outputs
    svf_step_last<<<grid, block, 0, stream>>>((const float4*)A, out);
}